// Round 1
// baseline (5805.689 us; speedup 1.0000x reference)
//
#include <hip/hip_runtime.h>
#include <hip/hip_bf16.h>
#include <math.h>

// ---------------- problem constants ----------------
#define AA 32
#define BB 2048
#define BP1 2049
#define CC 256
#define NROWS (AA * BP1)          // 65568
#define NHEAD 8
#define DHEAD 32
#define NBLK 3
#define FFN 1024

using bf16 = __hip_bfloat16;

__device__ __forceinline__ float bf2f(unsigned short u) {
    return __uint_as_float(((unsigned int)u) << 16);
}

// ---------------- row 0 of each batch: cls + bias ----------------
__global__ __launch_bounds__(256) void row0_k(float* __restrict__ out,
                                              const float* __restrict__ cls,
                                              const float* __restrict__ bias) {
    int i = blockIdx.x, t = threadIdx.x;
    size_t o = (size_t)i * BP1 * CC + t;
    out[o] = cls[i * CC + t] + bias[o];
}

// ---------------- layernorm: one wave per 256-wide row ----------------
__global__ __launch_bounds__(256) void ln_k(const float* __restrict__ in, float* __restrict__ out,
                                            const float* __restrict__ g, const float* __restrict__ b) {
    int row = blockIdx.x * 4 + (threadIdx.x >> 6);
    int lane = threadIdx.x & 63;
    const float4 v = *reinterpret_cast<const float4*>(in + (size_t)row * CC + lane * 4);
    float s = v.x + v.y + v.z + v.w;
    float sq = v.x * v.x + v.y * v.y + v.z * v.z + v.w * v.w;
    #pragma unroll
    for (int m = 1; m < 64; m <<= 1) { s += __shfl_xor(s, m); sq += __shfl_xor(sq, m); }
    float mu = s * (1.0f / CC);
    float var = sq * (1.0f / CC) - mu * mu;
    float rs = rsqrtf(var + 1e-5f);
    const float4 gg = *reinterpret_cast<const float4*>(g + lane * 4);
    const float4 bb = *reinterpret_cast<const float4*>(b + lane * 4);
    float4 o;
    o.x = (v.x - mu) * rs * gg.x + bb.x;
    o.y = (v.y - mu) * rs * gg.y + bb.y;
    o.z = (v.z - mu) * rs * gg.z + bb.z;
    o.w = (v.w - mu) * rs * gg.w + bb.w;
    *reinterpret_cast<float4*>(out + (size_t)row * CC + lane * 4) = o;
}

// ---------------- Wqkv pre-transpose: [a][x][h][d][k] -> [a][h][k][c], c = x*32+d ----------------
__global__ __launch_bounds__(256) void wqkv_t_k(const float* __restrict__ Wqkv, float* __restrict__ wt) {
    int idx = blockIdx.x * 256 + threadIdx.x;        // 589824 total
    int c = idx % 96;
    int k = (idx / 96) & 255;
    int h = (idx / (96 * 256)) & 7;
    int a = idx / (96 * 256 * 8);
    int x = c >> 5, d = c & 31;
    wt[idx] = Wqkv[((((size_t)a * 3 + x) * NHEAD + h) * DHEAD + d) * CC + k];
}

// ---------------- fused qkv gemm + rsa + imv (all f32) ----------------
// 32 rows per block, loop over 8 heads; wt layout [h][k 256][c 96]
__global__ __launch_bounds__(256) void qkv_k(const float* __restrict__ z,
                                             const float* __restrict__ wt,
                                             float* __restrict__ imv) {
    __shared__ float zs[32][257];
    __shared__ float wsh[64][100];
    __shared__ float qs[32][100];
    const int t = threadIdx.x;
    const int r0 = blockIdx.x * 32;

    #pragma unroll
    for (int rr = 0; rr < 32; ++rr)
        zs[rr][t] = z[(size_t)(r0 + rr) * CC + t];

    const int r = t >> 3;            // 0..31
    const int c0 = (t & 7) * 12;     // 0,12,..,84

    for (int h = 0; h < NHEAD; ++h) {
        float acc[12] = {};
        for (int kb = 0; kb < 4; ++kb) {
            __syncthreads();
            #pragma unroll
            for (int n = 0; n < 24; ++n) {          // 96*64/256
                int idx = n * 256 + t;
                int kk = idx / 96;
                int cc2 = idx - kk * 96;
                wsh[kk][cc2] = wt[((size_t)h * 256 + kb * 64 + kk) * 96 + cc2];
            }
            __syncthreads();
            #pragma unroll
            for (int kk = 0; kk < 64; ++kk) {
                float zv = zs[r][kb * 64 + kk];
                float4 w0 = *reinterpret_cast<const float4*>(&wsh[kk][c0]);
                float4 w1 = *reinterpret_cast<const float4*>(&wsh[kk][c0 + 4]);
                float4 w2 = *reinterpret_cast<const float4*>(&wsh[kk][c0 + 8]);
                acc[0] += zv * w0.x; acc[1]  += zv * w0.y; acc[2]  += zv * w0.z; acc[3]  += zv * w0.w;
                acc[4] += zv * w1.x; acc[5]  += zv * w1.y; acc[6]  += zv * w1.z; acc[7]  += zv * w1.w;
                acc[8] += zv * w2.x; acc[9]  += zv * w2.y; acc[10] += zv * w2.z; acc[11] += zv * w2.w;
            }
        }
        __syncthreads();             // previous head's rsa reads of qs done
        #pragma unroll
        for (int j = 0; j < 12; ++j) qs[r][c0 + j] = acc[j];
        __syncthreads();
        {
            int d0 = (t & 7) * 4;
            float p = 0.f;
            #pragma unroll
            for (int e = 0; e < 4; ++e) p += qs[r][d0 + e] * qs[r][32 + d0 + e];
            p += __shfl_xor(p, 1); p += __shfl_xor(p, 2); p += __shfl_xor(p, 4);
            float sc = p * 0.17677669529663689f;     // 1/sqrt(32)
            float4 o = make_float4(sc * qs[r][64 + d0], sc * qs[r][64 + d0 + 1],
                                   sc * qs[r][64 + d0 + 2], sc * qs[r][64 + d0 + 3]);
            *reinterpret_cast<float4*>(imv + (size_t)(r0 + r) * CC + h * DHEAD + d0) = o;
        }
    }
}

// ---------------- cumsum over seq (rows 0..B-1 within each batch), two-pass ----------------
__global__ __launch_bounds__(256) void cumsum1_k(float* __restrict__ imv, float* __restrict__ tot) {
    int i = blockIdx.x >> 3, ch = blockIdx.x & 7, c = threadIdx.x;
    size_t base = ((size_t)i * BP1 + ch * 256) * CC + c;
    float acc = 0.f;
    for (int j = 0; j < 256; ++j) {
        acc += imv[base + (size_t)j * CC];
        imv[base + (size_t)j * CC] = acc;
    }
    tot[((size_t)i * 8 + ch) * CC + c] = acc;
}

__global__ __launch_bounds__(256) void cumsum2_k(float* __restrict__ imv, const float* __restrict__ tot) {
    int i = blockIdx.x >> 3, ch = blockIdx.x & 7, c = threadIdx.x;
    if (ch == 0) return;
    float off = 0.f;
    for (int p = 0; p < ch; ++p) off += tot[((size_t)i * 8 + p) * CC + c];
    size_t base = ((size_t)i * BP1 + ch * 256) * CC + c;
    for (int j = 0; j < 256; ++j) imv[base + (size_t)j * CC] += off;
}

// ---------------- generic tiled fp32 gemm: Out(MxN) = A(MxK) * W(NxK)^T + epilogue ----------------
template<bool ABF16, bool OBF16, bool ROWMAP, bool BIAS2D, bool BIAS1D, bool RESID, bool GELU>
__global__ __launch_bounds__(256) void gemm_k(const void* __restrict__ Ap,
                                              const float* __restrict__ W,
                                              void* __restrict__ Op,
                                              const float* __restrict__ bias,
                                              int M, int K, int NC) {
    __shared__ float as[16][68];
    __shared__ float bs[16][68];
    const int t = threadIdx.x;
    const int m0 = blockIdx.x * 64;
    const int n0 = blockIdx.y * 64;
    const int ty = t >> 4, tx = t & 15;
    const int lm = t >> 2;            // 0..63
    const int lk = (t & 3) * 4;       // 0,4,8,12

    float acc[4][4] = {};

    for (int k0 = 0; k0 < K; k0 += 16) {
        __syncthreads();
        {   // stage A tile (transposed into [k][m])
            int row = m0 + lm;
            float4 v = make_float4(0.f, 0.f, 0.f, 0.f);
            if (row < M) {
                if (ABF16) {
                    const ushort4 u = *reinterpret_cast<const ushort4*>(
                        reinterpret_cast<const unsigned short*>(Ap) + (size_t)row * K + k0 + lk);
                    v.x = bf2f(u.x); v.y = bf2f(u.y); v.z = bf2f(u.z); v.w = bf2f(u.w);
                } else {
                    v = *reinterpret_cast<const float4*>(
                        reinterpret_cast<const float*>(Ap) + (size_t)row * K + k0 + lk);
                }
            }
            as[lk + 0][lm] = v.x; as[lk + 1][lm] = v.y; as[lk + 2][lm] = v.z; as[lk + 3][lm] = v.w;
        }
        {   // stage W tile (transposed into [k][n])
            const float4 v = *reinterpret_cast<const float4*>(W + (size_t)(n0 + lm) * K + k0 + lk);
            bs[lk + 0][lm] = v.x; bs[lk + 1][lm] = v.y; bs[lk + 2][lm] = v.z; bs[lk + 3][lm] = v.w;
        }
        __syncthreads();
        #pragma unroll
        for (int kk = 0; kk < 16; ++kk) {
            const float4 a4 = *reinterpret_cast<const float4*>(&as[kk][ty * 4]);
            const float4 b4 = *reinterpret_cast<const float4*>(&bs[kk][tx * 4]);
            float av[4] = {a4.x, a4.y, a4.z, a4.w};
            float bv[4] = {b4.x, b4.y, b4.z, b4.w};
            #pragma unroll
            for (int i = 0; i < 4; ++i)
                #pragma unroll
                for (int j = 0; j < 4; ++j)
                    acc[i][j] += av[i] * bv[j];
        }
    }

    #pragma unroll
    for (int i = 0; i < 4; ++i) {
        int row = m0 + ty * 4 + i;
        if (row >= M) continue;
        size_t g;
        if (ROWMAP) {
            int ib = row >> 11, j = row & 2047;          // B = 2048
            g = (size_t)ib * BP1 + 1 + j;
        } else {
            g = (size_t)row;
        }
        #pragma unroll
        for (int j = 0; j < 4; ++j) {
            int col = n0 + tx * 4 + j;
            float v = acc[i][j];
            if (BIAS1D) v += bias[col];
            if (BIAS2D) v += bias[g * NC + col];
            if (GELU)   v = 0.5f * v * (1.0f + erff(v * 0.70710678118654752f));
            size_t oi = g * NC + col;
            if (OBF16) {
                reinterpret_cast<bf16*>(Op)[oi] = __float2bfloat16(v);
            } else {
                float* O = reinterpret_cast<float*>(Op);
                if (RESID) v += O[oi];
                O[oi] = v;
            }
        }
    }
}

// ---------------- launch ----------------
extern "C" void kernel_launch(void* const* d_in, const int* in_sizes, int n_in,
                              void* d_out, int out_size, void* d_ws, size_t ws_size,
                              hipStream_t stream) {
    const float* x      = (const float*)d_in[0];
    const float* weight = (const float*)d_in[1];
    const float* bias   = (const float*)d_in[2];
    const float* cls    = (const float*)d_in[3];
    const float* Wqkv   = (const float*)d_in[4];
    const float* Wo     = (const float*)d_in[5];
    const float* ln1_g  = (const float*)d_in[6];
    const float* ln1_b  = (const float*)d_in[7];
    const float* ln2_g  = (const float*)d_in[8];
    const float* ln2_b  = (const float*)d_in[9];
    const float* fc1_w  = (const float*)d_in[10];
    const float* fc1_b  = (const float*)d_in[11];
    const float* fc2_w  = (const float*)d_in[12];
    const float* fc2_b  = (const float*)d_in[13];
    float* out = (float*)d_out;

    // workspace layout (bytes):
    //   z      [0,           67,141,632)   N*256 f32
    //   imv    [67,141,632, 134,283,264)   N*256 f32
    //   spare  [134,283,264, 201,424,896)  (h bf16 overlays imv+spare, dead-time disjoint)
    //   wt_all [201,424,896, 203,784,192)  3*8*256*96 f32
    //   tot    [203,784,192, 204,046,336)  32*8*256 f32
    char* ws = (char*)d_ws;
    constexpr size_t Z_OFF   = 0;
    constexpr size_t IMV_OFF = 67141632;
    constexpr size_t WT_OFF  = 201424896;
    constexpr size_t TOT_OFF = 203784192;
    float* z    = (float*)(ws + Z_OFF);
    float* imv  = (float*)(ws + IMV_OFF);
    bf16*  hbuf = (bf16*) (ws + IMV_OFF);   // N*1024 bf16, overlays imv+spare
    float* wt   = (float*)(ws + WT_OFF);
    float* tot  = (float*)(ws + TOT_OFF);

    row0_k<<<AA, 256, 0, stream>>>(out, cls, bias);
    wqkv_t_k<<<2304, 256, 0, stream>>>(Wqkv, wt);
    // embed: out[i,1+j,:] = x[i,j,:] @ weight^T + bias[i,1+j,:]
    gemm_k<false,false,true,true,false,false,false>
        <<<dim3(1024, 4), 256, 0, stream>>>(x, weight, out, bias, AA * BB, CC, CC);

    for (int a = 0; a < NBLK; ++a) {
        ln_k<<<NROWS / 4, 256, 0, stream>>>(out, z, ln1_g, ln1_b);
        qkv_k<<<NROWS / 32, 256, 0, stream>>>(z, wt + (size_t)a * 8 * 256 * 96, imv);
        cumsum1_k<<<256, 256, 0, stream>>>(imv, tot);
        cumsum2_k<<<256, 256, 0, stream>>>(imv, tot);
        // savespace += imv @ Wo[a]^T
        gemm_k<false,false,false,false,false,true,false>
            <<<dim3(1025, 4), 256, 0, stream>>>(imv, Wo + (size_t)a * CC * CC, out, nullptr, NROWS, CC, CC);
        ln_k<<<NROWS / 4, 256, 0, stream>>>(out, z, ln2_g, ln2_b);
        // h = gelu(z @ fc1_w^T + fc1_b), stored bf16
        gemm_k<false,true,false,false,true,false,true>
            <<<dim3(1025, 16), 256, 0, stream>>>(z, fc1_w, hbuf, fc1_b, NROWS, CC, FFN);
        // savespace += h @ fc2_w^T + fc2_b
        gemm_k<true,false,false,false,true,true,false>
            <<<dim3(1025, 4), 256, 0, stream>>>(hbuf, fc2_w, out, fc2_b, NROWS, FFN, CC);
    }
}